// Round 5
// baseline (1307.052 us; speedup 1.0000x reference)
//
#include <hip/hip_runtime.h>
#include <stdint.h>

// Problem dims (fixed)
#define B_  32
#define S_  2048
#define H_  256
#define Z_  64

typedef unsigned short u16;
typedef __attribute__((ext_vector_type(8))) short bf16x8;   // 8 bf16 in 4 VGPRs
typedef __attribute__((ext_vector_type(4))) float f32x4;

__device__ __forceinline__ u16 f2bf(float f) {
    unsigned int x = __float_as_uint(f);
    x = (x + 0x7fffu + ((x >> 16) & 1u)) >> 16;   // RNE
    return (u16)x;
}
__device__ __forceinline__ float bf2f(u16 u) {
    return __uint_as_float(((unsigned int)u) << 16);
}

// async global->LDS, 16B per lane. LDS dest is wave-uniform base + lane*16.
__device__ __forceinline__ void gl2lds16(const void* g, void* l) {
    __builtin_amdgcn_global_load_lds(
        (const __attribute__((address_space(1))) unsigned int*)g,
        (__attribute__((address_space(3))) unsigned int*)l,
        16, 0, 0);
}

// ---------------------------------------------------------------------------
// K_detect: fp32 (flag=1) vs bf16 (flag=0) from Wq's even-indexed u16s.
// ---------------------------------------------------------------------------
__global__ void detect_kernel(const u16* __restrict__ wq, int* __restrict__ flag) {
    __shared__ int tot;
    const int t = threadIdx.x;
    if (t == 0) tot = 0;
    __syncthreads();
    int cnt = 0;
    #pragma unroll
    for (int r = 0; r < 16; ++r) {
        u16 u = wq[(r * 256 + t) * 2];
        int e = (u >> 7) & 0xFF;
        cnt += (u == 0 || (e >= 107 && e <= 132)) ? 1 : 0;
    }
    atomicAdd(&tot, cnt);
    __syncthreads();
    if (t == 0) *flag = (tot < 2048) ? 1 : 0;    // 1 = fp32 inputs
}

// ---------------------------------------------------------------------------
// prep roles (device bodies) — fused into one dispatch.
// ---------------------------------------------------------------------------
__device__ void role_mask(int bx, const void* __restrict__ raw, int* __restrict__ mi) {
    __shared__ int isByte;
    const int t = threadIdx.x;
    if (t == 0) isByte = 0;
    __syncthreads();
    const unsigned int* w = (const unsigned int*)raw;
    if (w[t & 255] > 1u) isByte = 1;
    __syncthreads();
    int e = bx * 256 + t;
    int val;
    if (isByte) val = ((const unsigned char*)raw)[e] ? 1 : 0;
    else        val = w[e] ? 1 : 0;
    mi[e] = val;
}

__device__ void role_wsplit(int bx, int by, int fp32,
                            const void* __restrict__ Wq, const void* __restrict__ Wk,
                            u16* __restrict__ WqTh, u16* __restrict__ WqTl,
                            u16* __restrict__ WkTh, u16* __restrict__ WkTl) {
    const void* src = by ? Wk : Wq;
    u16* oh = by ? WkTh : WqTh;
    u16* ol = by ? WkTl : WqTl;
    int base = bx * 1024;
    #pragma unroll
    for (int r = 0; r < 4; ++r) {
        int idx = base + r * 256 + threadIdx.x;
        int d = idx >> 8, h = idx & 255;
        float v = fp32 ? ((const float*)src)[h * 256 + d]
                       : bf2f(((const u16*)src)[h * 256 + d]);
        u16 hi = f2bf(v);
        oh[idx] = hi;
        ol[idx] = f2bf(v - bf2f(hi));
    }
}

// G[d][h] = sum_e Wq[d,e] * Wk[h,e]  (fp32), split hi/lo.
// This is the proj "transposed weight" for k' = enc @ G^T.
__device__ void role_gmat(int d, int fp32,
                          const void* __restrict__ Wq, const void* __restrict__ Wk,
                          u16* __restrict__ Gh, u16* __restrict__ Gl) {
    __shared__ float wqrow[256];
    const int t = threadIdx.x;
    wqrow[t] = fp32 ? ((const float*)Wq)[d * 256 + t]
                    : bf2f(((const u16*)Wq)[d * 256 + t]);
    __syncthreads();
    float s = 0.f;
    if (fp32) {
        const float* wk = (const float*)Wk + (size_t)t * 256;
        for (int e = 0; e < 256; ++e) s += wqrow[e] * wk[e];
    } else {
        const u16* wk = (const u16*)Wk + (size_t)t * 256;
        for (int e = 0; e < 256; ++e) s += wqrow[e] * bf2f(wk[e]);
    }
    u16 hi = f2bf(s);
    Gh[d * 256 + t] = hi;
    Gl[d * 256 + t] = f2bf(s - bf2f(hi));
}

__device__ void role_xsplit(int bx, int by, int fp32,
                            const void* __restrict__ dec, const void* __restrict__ enc,
                            u16* __restrict__ Xdh, u16* __restrict__ Xdl,
                            u16* __restrict__ Xeh, u16* __restrict__ Xel) {
    const void* src = by ? enc : dec;
    u16* oh = by ? Xeh : Xdh;
    u16* ol = by ? Xel : Xdl;
    const int t = threadIdx.x;
    const size_t blockbase = (size_t)bx * 4096;
    if (fp32) {
        const float4* s4 = (const float4*)src;
        #pragma unroll
        for (int j = 0; j < 4; ++j) {
            size_t idx = blockbase + j * 1024 + t * 4;
            float4 v = s4[idx >> 2];
            u16 h0 = f2bf(v.x), h1 = f2bf(v.y), h2 = f2bf(v.z), h3 = f2bf(v.w);
            u16 l0 = f2bf(v.x - bf2f(h0)), l1 = f2bf(v.y - bf2f(h1));
            u16 l2 = f2bf(v.z - bf2f(h2)), l3 = f2bf(v.w - bf2f(h3));
            uint2 ph, pl;
            ph.x = (unsigned)h0 | ((unsigned)h1 << 16);
            ph.y = (unsigned)h2 | ((unsigned)h3 << 16);
            pl.x = (unsigned)l0 | ((unsigned)l1 << 16);
            pl.y = (unsigned)l2 | ((unsigned)l3 << 16);
            ((uint2*)oh)[idx >> 2] = ph;
            ((uint2*)ol)[idx >> 2] = pl;
        }
    } else {
        const uint2* s2 = (const uint2*)src;
        #pragma unroll
        for (int j = 0; j < 4; ++j) {
            size_t idx = blockbase + j * 1024 + t * 4;
            uint2 r = s2[idx >> 2];
            uint2 z; z.x = 0u; z.y = 0u;
            ((uint2*)oh)[idx >> 2] = r;
            ((uint2*)ol)[idx >> 2] = z;
        }
    }
}

__device__ void role_vproj(int bx, int dc, int fp32,
                           const void* __restrict__ Lraw,
                           const void* __restrict__ Wvraw, u16* __restrict__ vT) {
    __shared__ float wv[64 * 16];
    const int t = threadIdx.x;
    #pragma unroll
    for (int r = 0; r < 4; ++r) {
        int idx = r * 256 + t;
        int z = idx >> 4, dd = idx & 15;
        wv[idx] = fp32 ? ((const float*)Wvraw)[z * 64 + dc * 16 + dd]
                       : bf2f(((const u16*)Wvraw)[z * 64 + dc * 16 + dd]);
    }
    __syncthreads();
    const int flat = bx * 256 + t;
    const int b = flat >> 11, s = flat & 2047;

    float lz[64];
    if (fp32) {
        const float4* lr = (const float4*)((const float*)Lraw + (size_t)flat * 64);
        #pragma unroll
        for (int c = 0; c < 16; ++c) {
            float4 v = lr[c];
            lz[c * 4 + 0] = v.x; lz[c * 4 + 1] = v.y;
            lz[c * 4 + 2] = v.z; lz[c * 4 + 3] = v.w;
        }
    } else {
        const uint4* lr = (const uint4*)((const u16*)Lraw + (size_t)flat * 64);
        #pragma unroll
        for (int c = 0; c < 8; ++c) {
            uint4 v = lr[c];
            unsigned wd[4] = {v.x, v.y, v.z, v.w};
            #pragma unroll
            for (int e2 = 0; e2 < 4; ++e2) {
                lz[c * 8 + e2 * 2 + 0] = bf2f((u16)(wd[e2] & 0xffffu));
                lz[c * 8 + e2 * 2 + 1] = bf2f((u16)(wd[e2] >> 16));
            }
        }
    }

    float acc[16];
    #pragma unroll
    for (int d = 0; d < 16; ++d) acc[d] = 0.f;
    for (int z = 0; z < 64; ++z) {
        float lv = lz[z];
        const float4* wrow = (const float4*)&wv[z * 16];
        #pragma unroll
        for (int d4 = 0; d4 < 4; ++d4) {
            float4 wq = wrow[d4];
            acc[d4 * 4 + 0] += lv * wq.x;
            acc[d4 * 4 + 1] += lv * wq.y;
            acc[d4 * 4 + 2] += lv * wq.z;
            acc[d4 * 4 + 3] += lv * wq.w;
        }
    }
    #pragma unroll
    for (int d = 0; d < 16; ++d)
        vT[((size_t)b * 64 + dc * 16 + d) * S_ + s] = f2bf(acc[d]);
}

// One dispatch for all prep work. Block ranges: [0,n_xs) xsplit,
// then 1024 vproj, then 128 wsplit, then 256 mask, then 256 gmat.
__global__ __launch_bounds__(256) void prep_kernel(
        const int* __restrict__ flagp, int n_xs,
        const void* __restrict__ dec, const void* __restrict__ enc,
        u16* __restrict__ Xdh, u16* __restrict__ Xdl,
        u16* __restrict__ Xeh, u16* __restrict__ Xel,
        const void* __restrict__ Lraw, const void* __restrict__ Wvraw,
        u16* __restrict__ vT,
        const void* __restrict__ Wq, const void* __restrict__ Wk,
        u16* __restrict__ WqTh, u16* __restrict__ WqTl,
        u16* __restrict__ WkTh, u16* __restrict__ WkTl,
        u16* __restrict__ Gh, u16* __restrict__ Gl,
        const void* __restrict__ mraw, int* __restrict__ maskI)
{
    const int fp32 = *flagp;
    int r = blockIdx.x;
    if (r < n_xs) {
        role_xsplit(r & 4095, r >> 12, fp32, dec, enc, Xdh, Xdl, Xeh, Xel);
        return;
    }
    r -= n_xs;
    if (r < 1024) {
        role_vproj(r & 255, r >> 8, fp32, Lraw, Wvraw, vT);
        return;
    }
    r -= 1024;
    if (r < 128) {
        role_wsplit(r & 63, r >> 6, fp32, Wq, Wk, WqTh, WqTl, WkTh, WkTl);
        return;
    }
    r -= 128;
    if (r < 256) {
        role_mask(r, mraw, maskI);
        return;
    }
    r -= 256;
    role_gmat(r, fp32, Wq, Wk, Gh, Gl);
}

// ---------------------------------------------------------------------------
// K0: P = X @ W via 3-product split (single-buffer, R3 structure).
// blockIdx.z selects problem set; XOR-swizzled staging (pos = chunk ^ (row&7)).
// ---------------------------------------------------------------------------
__global__ __launch_bounds__(256, 2) void proj_kernel(
        const int* __restrict__ flagp, int use_xsplit,
        const float* __restrict__ Xf0, const u16* __restrict__ Xu0,
        const u16* __restrict__ Xh0, const u16* __restrict__ Xl0,
        const u16* __restrict__ WTh0, const u16* __restrict__ WTl0,
        u16* __restrict__ Ph0, u16* __restrict__ Pl0,
        const float* __restrict__ Xf1, const u16* __restrict__ Xu1,
        const u16* __restrict__ Xh1, const u16* __restrict__ Xl1,
        const u16* __restrict__ WTh1, const u16* __restrict__ WTl1,
        u16* __restrict__ Ph1, u16* __restrict__ Pl1)
{
    __shared__ __align__(16) u16 lds[16384];   // A slab [0,8192) u16, B slab [8192,16384)
    const int z = blockIdx.z;
    const float* Xf = z ? Xf1 : Xf0;
    const u16*   Xu = z ? Xu1 : Xu0;
    const u16*   Xh = z ? Xh1 : Xh0;
    const u16*   Xl = z ? Xl1 : Xl0;
    const u16*  WTh = z ? WTh1 : WTh0;
    const u16*  WTl = z ? WTl1 : WTl0;
    u16* Ph = z ? Ph1 : Ph0;
    u16* Pl = z ? Pl1 : Pl0;

    const int fp32 = *flagp;
    const int t = threadIdx.x;
    const int lane = t & 63, w = t >> 6;
    const int i0 = blockIdx.x * 128;
    const int d0 = blockIdx.y * 128;
    const int rh = w >> 1, ch = w & 1;
    const int l15 = lane & 15;
    const int c0 = lane >> 4;                 // fragment chunk (0..3)

    const int srow = t >> 3;                  // base row (rep adds 32)
    const int scp  = t & 7;                   // chunk position in row
    const int sc   = scp ^ (srow & 7);        // logical chunk held there
    const int scol = (sc & 3) * 8;            // k-col offset within 32
    const int slo  = sc & 4;                  // lo half?

    f32x4 acc[4][4];
    #pragma unroll
    for (int a = 0; a < 4; ++a)
        #pragma unroll
        for (int c = 0; c < 4; ++c) acc[a][c] = (f32x4){0.f, 0.f, 0.f, 0.f};

    for (int ks = 0; ks < 8; ++ks) {
        const int kc = ks * 32;
        {
            const u16* wsrc = slo ? WTl : WTh;
            #pragma unroll
            for (int rep = 0; rep < 4; ++rep) {
                int s = t + rep * 256;        // 0..1023
                int row = srow + rep * 32;
                gl2lds16(wsrc + (size_t)(d0 + row) * H_ + kc + scol, lds + 8192 + s * 8);
            }
        }
        if (use_xsplit) {
            const u16* xsrc = slo ? Xl : Xh;
            #pragma unroll
            for (int rep = 0; rep < 4; ++rep) {
                int s = t + rep * 256;
                int row = srow + rep * 32;
                gl2lds16(xsrc + (size_t)(i0 + row) * H_ + kc + scol, lds + s * 8);
            }
        } else if (fp32) {
            #pragma unroll
            for (int rep = 0; rep < 2; ++rep) {
                int s = t + rep * 256;
                int r = s >> 2, c8 = s & 3;
                const float4* src = (const float4*)(Xf + (size_t)(i0 + r) * H_ + kc + c8 * 8);
                float4 x0 = src[0], x1 = src[1];
                float xs[8] = {x0.x, x0.y, x0.z, x0.w, x1.x, x1.y, x1.z, x1.w};
                unsigned hh[8], ll[8];
                #pragma unroll
                for (int j = 0; j < 8; ++j) {
                    u16 hb = f2bf(xs[j]);
                    hh[j] = hb;
                    ll[j] = f2bf(xs[j] - bf2f(hb));
                }
                uint4 ph, pl;
                ph.x = hh[0] | (hh[1] << 16); ph.y = hh[2] | (hh[3] << 16);
                ph.z = hh[4] | (hh[5] << 16); ph.w = hh[6] | (hh[7] << 16);
                pl.x = ll[0] | (ll[1] << 16); pl.y = ll[2] | (ll[3] << 16);
                pl.z = ll[4] | (ll[5] << 16); pl.w = ll[6] | (ll[7] << 16);
                int posH = c8 ^ (r & 7);
                *(uint4*)(lds + r * 64 + posH * 8) = ph;
                *(uint4*)(lds + r * 64 + (posH ^ 4) * 8) = pl;
            }
        } else {
            #pragma unroll
            for (int rep = 0; rep < 2; ++rep) {
                int s = t + rep * 256;
                int r = s >> 2, c8 = s & 3;
                uint4 raw = *(const uint4*)(Xu + (size_t)(i0 + r) * H_ + kc + c8 * 8);
                int posH = c8 ^ (r & 7);
                *(uint4*)(lds + r * 64 + posH * 8) = raw;
                *(uint4*)(lds + r * 64 + (posH ^ 4) * 8) = (uint4){0u, 0u, 0u, 0u};
            }
        }
        __syncthreads();
        bf16x8 ah[4], al[4], bh[4], bl[4];
        #pragma unroll
        for (int f = 0; f < 4; ++f) {
            int ra = rh * 64 + f * 16 + l15;
            int rb = ch * 64 + f * 16 + l15;
            int pa = c0 ^ (ra & 7);
            int pb = c0 ^ (rb & 7);
            ah[f] = *(const bf16x8*)(lds + ra * 64 + pa * 8);
            al[f] = *(const bf16x8*)(lds + ra * 64 + (pa ^ 4) * 8);
            bh[f] = *(const bf16x8*)(lds + 8192 + rb * 64 + pb * 8);
            bl[f] = *(const bf16x8*)(lds + 8192 + rb * 64 + (pb ^ 4) * 8);
        }
        #pragma unroll
        for (int fr = 0; fr < 4; ++fr)
            #pragma unroll
            for (int fc = 0; fc < 4; ++fc) {
                acc[fr][fc] = __builtin_amdgcn_mfma_f32_16x16x32_bf16(al[fr], bh[fc], acc[fr][fc], 0, 0, 0);
                acc[fr][fc] = __builtin_amdgcn_mfma_f32_16x16x32_bf16(ah[fr], bl[fc], acc[fr][fc], 0, 0, 0);
                acc[fr][fc] = __builtin_amdgcn_mfma_f32_16x16x32_bf16(ah[fr], bh[fc], acc[fr][fc], 0, 0, 0);
            }
        __syncthreads();
    }
    #pragma unroll
    for (int fr = 0; fr < 4; ++fr)
        #pragma unroll
        for (int fc = 0; fc < 4; ++fc)
            #pragma unroll
            for (int reg = 0; reg < 4; ++reg) {
                float v = acc[fr][fc][reg];
                int i = i0 + rh * 64 + fr * 16 + (lane >> 4) * 4 + reg;
                int d = d0 + ch * 64 + fc * 16 + l15;
                u16 hi = f2bf(v);
                u16 lo = f2bf(v - bf2f(hi));
                size_t off = (size_t)i * H_ + d;
                Ph[off] = hi;
                Pl[off] = lo;
            }
}

// ---------------------------------------------------------------------------
// K1: logits tile 256x256 (512 threads, 8 waves = 2x4). 3-product split,
// XOR-swizzled staging, single-buffer 2-barrier k-loop. Column max/sum over
// the 256-row tile (8 i-tiles of 256 per batch); e-tile streamed out via LDS
// in two 128-col passes (pad stride 136 u16).
// ---------------------------------------------------------------------------
#define NIT_ 8
#define EST_ 136
__global__ __launch_bounds__(512, 2) void qk_kernel(
        const u16* __restrict__ qh, const u16* __restrict__ ql,
        const u16* __restrict__ kh, const u16* __restrict__ kl,
        const int* __restrict__ maskI, u16* __restrict__ attnB,
        float* __restrict__ attnF, u16* __restrict__ stageB, int use_stage,
        float* __restrict__ m_p, float* __restrict__ s_p,
        int b0, const int* __restrict__ flagp)
{
    __shared__ __align__(16) char smem[74752];
    u16*  stage = (u16*)smem;                 // q slab [0,16384) u16, k slab [16384,32768)
    u16*  etile = (u16*)smem;                 // 256 x EST_ u16 = 69632 B (reuses stage)
    float* cmax = (float*)(smem + 69632);     // [2][256]
    float* csum = (float*)(smem + 71680);     // [2][256]
    float* mrow = (float*)(smem + 73728);     // [256]

    const int fp32 = *flagp;
    const int t = threadIdx.x;
    const int lane = t & 63, w = t >> 6;
    const int wr = w >> 2, wc = w & 3;
    const int jt = blockIdx.x, it = blockIdx.y, bz = blockIdx.z;
    const int b = b0 + bz;
    const int i0 = it * 256, j0 = jt * 256;
    const int l15 = lane & 15;
    const int c0 = lane >> 4;

    if (t < 256) mrow[t] = (maskI[b * S_ + i0 + t] != 0) ? 1.f : 0.f;

    const size_t qbase = ((size_t)bz * S_ + i0) * H_;
    const size_t kbase = ((size_t)bz * S_ + j0) * H_;

    const int srow = t >> 3;                  // 0..63, rep adds 64
    const int scp  = t & 7;
    const int sc   = scp ^ (srow & 7);
    const int scol = (sc & 3) * 8;
    const u16* qsrc = (sc & 4) ? ql : qh;
    const u16* ksrc = (sc & 4) ? kl : kh;

    f32x4 acc[8][4];
    #pragma unroll
    for (int a = 0; a < 8; ++a)
        #pragma unroll
        for (int c = 0; c < 4; ++c) acc[a][c] = (f32x4){0.f, 0.f, 0.f, 0.f};

    for (int ks = 0; ks < 8; ++ks) {
        const int kc = ks * 32;
        #pragma unroll
        for (int rep = 0; rep < 4; ++rep) {
            int s = t + rep * 512;            // 0..2047
            int row = srow + rep * 64;
            gl2lds16(qsrc + qbase + (size_t)row * H_ + kc + scol, stage + s * 8);
            gl2lds16(ksrc + kbase + (size_t)row * H_ + kc + scol, stage + 16384 + s * 8);
        }
        __syncthreads();
        bf16x8 bhf[4], blf[4];
        #pragma unroll
        for (int f = 0; f < 4; ++f) {
            int rb = wc * 64 + f * 16 + l15;
            int pb = c0 ^ (rb & 7);
            bhf[f] = *(const bf16x8*)(stage + 16384 + rb * 64 + pb * 8);
            blf[f] = *(const bf16x8*)(stage + 16384 + rb * 64 + (pb ^ 4) * 8);
        }
        #pragma unroll
        for (int fr = 0; fr < 8; ++fr) {
            int ra = wr * 128 + fr * 16 + l15;
            int pa = c0 ^ (ra & 7);
            bf16x8 ahf = *(const bf16x8*)(stage + ra * 64 + pa * 8);
            bf16x8 alf = *(const bf16x8*)(stage + ra * 64 + (pa ^ 4) * 8);
            #pragma unroll
            for (int fc = 0; fc < 4; ++fc) {
                acc[fr][fc] = __builtin_amdgcn_mfma_f32_16x16x32_bf16(alf, bhf[fc], acc[fr][fc], 0, 0, 0);
                acc[fr][fc] = __builtin_amdgcn_mfma_f32_16x16x32_bf16(ahf, blf[fc], acc[fr][fc], 0, 0, 0);
                acc[fr][fc] = __builtin_amdgcn_mfma_f32_16x16x32_bf16(ahf, bhf[fc], acc[fr][fc], 0, 0, 0);
            }
        }
        __syncthreads();
    }

    // mask rows, scale, per-column (over i) max
    const float inv_t = 0.0625f;
    float mloc[4] = {-3e38f, -3e38f, -3e38f, -3e38f};
    #pragma unroll
    for (int fr = 0; fr < 8; ++fr)
        #pragma unroll
        for (int reg = 0; reg < 4; ++reg) {
            float keep = mrow[wr * 128 + fr * 16 + c0 * 4 + reg];
            #pragma unroll
            for (int fc = 0; fc < 4; ++fc) {
                float l = acc[fr][fc][reg] * inv_t;
                l = (keep != 0.f) ? l : -1e9f;
                acc[fr][fc][reg] = l;
                mloc[fc] = fmaxf(mloc[fc], l);
            }
        }
    #pragma unroll
    for (int fc = 0; fc < 4; ++fc) {
        mloc[fc] = fmaxf(mloc[fc], __shfl_xor(mloc[fc], 16, 64));
        mloc[fc] = fmaxf(mloc[fc], __shfl_xor(mloc[fc], 32, 64));
    }
    if (lane < 16) {
        #pragma unroll
        for (int fc = 0; fc < 4; ++fc)
            cmax[wr * 256 + wc * 64 + fc * 16 + lane] = mloc[fc];
    }
    __syncthreads();

    float mcol[4];
    #pragma unroll
    for (int fc = 0; fc < 4; ++fc) {
        int c = wc * 64 + fc * 16 + l15;
        mcol[fc] = fmaxf(cmax[c], cmax[256 + c]);
    }

    // two 128-col passes: exp into LDS etile, stream out
    float sloc[4] = {0.f, 0.f, 0.f, 0.f};
    const int myp = wc >> 1;
    const int lcb = (wc & 1) * 64;
    for (int p = 0; p < 2; ++p) {
        __syncthreads();                      // etile free (k-loop done / prev pass streamed)
        if (myp == p) {
            #pragma unroll
            for (int fr = 0; fr < 8; ++fr)
                #pragma unroll
                for (int reg = 0; reg < 4; ++reg) {
                    int row = wr * 128 + fr * 16 + c0 * 4 + reg;
                    #pragma unroll
                    for (int fc = 0; fc < 4; ++fc) {
                        float e = __expf(acc[fr][fc][reg] - mcol[fc]);
                        sloc[fc] += e;
                        etile[row * EST_ + lcb + fc * 16 + l15] = f2bf(e);
                    }
                }
        }
        __syncthreads();
        const size_t abase = ((size_t)b * S_ + i0) * S_ + j0 + p * 128;
        if (fp32) {
            if (use_stage) {
                #pragma unroll
                for (int rep = 0; rep < 8; ++rep) {
                    int g = t + rep * 512;    // 0..4095
                    int row = g >> 4, c4 = g & 15;
                    *(uint4*)(stageB + abase + (size_t)row * S_ + c4 * 8) =
                        *(const uint4*)(etile + row * EST_ + c4 * 8);
                }
            } else {
                #pragma unroll
                for (int rep = 0; rep < 8; ++rep) {
                    int g = t + rep * 512;
                    int row = g >> 4, c4 = g & 15;
                    const u16* src = etile + row * EST_ + c4 * 8;
                    float* gp = attnF + abase + (size_t)row * S_ + c4 * 8;
                    float4 f0, f1;
                    f0.x = bf2f(src[0]); f0.y = bf2f(src[1]); f0.z = bf2f(src[2]); f0.w = bf2f(src[3]);
                    f1.x = bf2f(src[4]); f1.y = bf2f(src[5]); f1.z = bf2f(src[6]); f1.w = bf2f(src[7]);
                    *(float4*)gp = f0;
                    *(float4*)(gp + 4) = f1;
                }
            }
        } else {
            #pragma unroll
            for (int rep = 0; rep < 8; ++rep) {
                int g = t + rep * 512;
                int row = g >> 4, c4 = g & 15;
                *(uint4*)(attnB + abase + (size_t)row * S_ + c4 * 8) =
                    *(const uint4*)(etile + row * EST_ + c4 * 8);
            }
        }
    }

    #pragma unroll
    for (int fc = 0; fc < 4; ++fc) {
        sloc[fc] += __shfl_xor(sloc[fc], 16, 64);
        sloc[fc] += __shfl_xor(sloc[fc], 32, 64);
    }
    if (lane < 16) {
        #pragma unroll
        for (int fc = 0; fc < 4; ++fc)
            csum[wr * 256 + wc * 64 + fc * 16 + lane] = sloc[fc];
    }
    __syncthreads();

    if (t < 256) {
        float m = fmaxf(cmax[t], cmax[256 + t]);
        float sres = csum[t] + csum[256 + t];
        size_t so = ((size_t)b * NIT_ + it) * S_ + j0 + t;
        m_p[so] = m;
        s_p[so] = sres;
    }
}

// ---------------------------------------------------------------------------
// K2: scale[b][it][j] = exp(m_p - M) / L   (NIT_=8 i-tiles of 256 rows)
// ---------------------------------------------------------------------------
__global__ __launch_bounds__(256) void stats_kernel(
        const float* __restrict__ m_p, const float* __restrict__ s_p, float* __restrict__ scl)
{
    int id = blockIdx.x * 256 + threadIdx.x;
    int b = id >> 11, j = id & 2047;
    float mv[NIT_];
    float M = -3e38f;
    #pragma unroll
    for (int itile = 0; itile < NIT_; ++itile) {
        mv[itile] = m_p[((size_t)b * NIT_ + itile) * S_ + j];
        M = fmaxf(M, mv[itile]);
    }
    float L = 0.f;
    #pragma unroll
    for (int itile = 0; itile < NIT_; ++itile)
        L += s_p[((size_t)b * NIT_ + itile) * S_ + j] * __expf(mv[itile] - M);
    float invL = (L > 0.f) ? (1.f / L) : 0.f;
    #pragma unroll
    for (int itile = 0; itile < NIT_; ++itile)
        scl[((size_t)b * NIT_ + itile) * S_ + j] = __expf(mv[itile] - M) * invL;
}

// ---------------------------------------------------------------------------
// K3: out = rawE @ (scl .* vT) AND fused attn finalize (attn = rawE * scl).
// it is a 128-row tile index (0..15); qk i-tiles are 256 rows -> scl it>>1.
// ---------------------------------------------------------------------------
__global__ __launch_bounds__(256, 2) void av_gemm_kernel(
        const u16* __restrict__ vT, const float* __restrict__ scl,
        const u16* __restrict__ stageB, u16* __restrict__ attnB,
        float* __restrict__ attnF,
        u16* __restrict__ outB, float* __restrict__ outF,
        const int* __restrict__ flagp)
{
    __shared__ __align__(16) u16 lds_attn[128 * 128];   // rows of 16 chunks, pos = c ^ (row&15)
    __shared__ __align__(16) u16 lds_vt[64 * 128];      // rows of 16 chunks, pos = c ^ (d&15)
    const int fp32 = *flagp;
    const u16* srcE = fp32 ? stageB : attnB;
    const int t = threadIdx.x;
    const int lane = t & 63, w = t >> 6;
    const int it = blockIdx.x, b = blockIdx.y;
    const int i0 = it * 128;
    const int l15 = lane & 15;

    const int acp = t & 15;                       // position
    const int arow0 = t >> 4;                     // base row (rep adds 16)
    const int ac = acp ^ (arow0 & 15);            // logical chunk (const across reps)
    const int vpos = (t & 15) ^ (t >> 4);
    const int j8 = (t & 15) * 8;
    const size_t sclbase = ((size_t)b * NIT_ + (it >> 1)) * S_;

    f32x4 acc[2][4];
    #pragma unroll
    for (int a = 0; a < 2; ++a)
        #pragma unroll
        for (int c = 0; c < 4; ++c) acc[a][c] = (f32x4){0.f, 0.f, 0.f, 0.f};

    for (int jt = 0; jt < 16; ++jt) {
        const int j0 = jt * 128;
        __syncthreads();                          // protect prev iter's LDS reads
        const size_t abase = ((size_t)b * S_ + i0) * S_ + j0;
        #pragma unroll
        for (int rep = 0; rep < 8; ++rep) {
            int s = t + rep * 256;
            int row = arow0 + rep * 16;
            gl2lds16(srcE + abase + (size_t)row * S_ + ac * 8, lds_attn + s * 8);
        }
        // scl for vT staging chunk (j8) and for epilogue chunk (ac*8)
        float sc[8], esc[8];
        {
            const float4* sp = (const float4*)(scl + sclbase + j0 + j8);
            float4 s0 = sp[0], s1 = sp[1];
            sc[0] = s0.x; sc[1] = s0.y; sc[2] = s0.z; sc[3] = s0.w;
            sc[4] = s1.x; sc[5] = s1.y; sc[6] = s1.z; sc[7] = s1.w;
            const float4* ep = (const float4*)(scl + sclbase + j0 + ac * 8);
            float4 e0 = ep[0], e1 = ep[1];
            esc[0] = e0.x; esc[1] = e0.y; esc[2] = e0.z; esc[3] = e0.w;
            esc[4] = e1.x; esc[5] = e1.y; esc[6] = e1.z; esc[7] = e1.w;
        }
        #pragma unroll
        for (int rep = 0; rep < 4; ++rep) {
            int d = (t >> 4) + rep * 16;
            uint4 raw = *(const uint4*)(vT + ((size_t)b * 64 + d) * S_ + j0 + j8);
            unsigned wd[4] = {raw.x, raw.y, raw.z, raw.w};
            #pragma unroll
            for (int e2 = 0; e2 < 4; ++e2) {
                float f0 = bf2f((u16)(wd[e2] & 0xffffu)) * sc[e2 * 2];
                float f1 = bf2f((u16)(wd[e2] >> 16))     * sc[e2 * 2 + 1];
                wd[e2] = (unsigned)f2bf(f0) | ((unsigned)f2bf(f1) << 16);
            }
            uint4 pk; pk.x = wd[0]; pk.y = wd[1]; pk.z = wd[2]; pk.w = wd[3];
            *(uint4*)(lds_vt + d * 128 + vpos * 8) = pk;
        }
        __syncthreads();                          // drains gl2lds + ds_writes

        // ---- fused attn finalize: read back own raw-e chunks, scale, write ----
        #pragma unroll
        for (int rep = 0; rep < 8; ++rep) {
            int s = t + rep * 256;
            int row = arow0 + rep * 16;
            uint4 pk = *(const uint4*)(lds_attn + s * 8);
            unsigned wd[4] = {pk.x, pk.y, pk.z, pk.w};
            float f[8];
            f[0] = bf2f((u16)(wd[0] & 0xffffu)) * esc[0];
            f[1] = bf2f((u16)(wd[0] >> 16))     * esc[1];
            f[2] = bf2f((u16)(wd[1] & 0xffffu)) * esc[2];
            f[3] = bf2f((u16)(wd[1] >> 16))     * esc[3];
            f[4] = bf2f((u16)(wd[2] & 0xffffu)) * esc[4];
            f[5] = bf2f((u16)(wd[2] >> 16))     * esc[5];
            f[6] = bf2f((u16)(wd[3] & 0xffffu)) * esc[6];
            f[7] = bf2f((u16)(wd[3] >> 16))     * esc[7];
            size_t ga = abase + (size_t)row * S_ + ac * 8;
            if (fp32) {
                float4 o0, o1;
                o0.x = f[0]; o0.y = f[1]; o0.z = f[2]; o0.w = f[3];
                o1.x = f[4]; o1.y = f[5]; o1.z = f[6]; o1.w = f[7];
                *(float4*)(attnF + ga) = o0;
                *(float4*)(attnF + ga + 4) = o1;
            } else {
                uint4 o;
                o.x = (unsigned)f2bf(f[0]) | ((unsigned)f2bf(f[1]) << 16);
                o.y = (unsigned)f2bf(f[2]) | ((unsigned)f2bf(f[3]) << 16);
                o.z = (unsigned)f2bf(f[4]) | ((unsigned)f2bf(f[5]) << 16);
                o.w = (unsigned)f2bf(f[6]) | ((unsigned)f2bf(f[7]) << 16);
                *(uint4*)(attnB + ga) = o;
            }
        }

        #pragma unroll
        for (int ksj = 0; ksj < 4; ++ksj) {
            int ck = ksj * 4 + (lane >> 4);
            int pA = ck ^ l15;
            int rA0 = w * 32 + l15, rA1 = w * 32 + 16 + l15;
            bf16x8 a0 = *(const bf16x8*)(lds_attn + rA0 * 128 + pA * 8);
            bf16x8 a1 = *(const bf16x8*)(lds_attn + rA1 * 128 + pA * 8);
            bf16x8 bb[4];
            #pragma unroll
            for (int fc = 0; fc < 4; ++fc) {
                int d = fc * 16 + l15;
                bb[fc] = *(const bf16x8*)(lds_vt + d * 128 + pA * 8);
            }
            #pragma unroll
            for (int fc = 0; fc < 4; ++fc) {
                acc[0][fc] = __builtin_amdgcn_mfma_f32_16x16x32_bf16(a0, bb[fc], acc[0][fc], 0, 0, 0);
                acc[1][fc] = __builtin_amdgcn_mfma_f32_16x16x32_bf16(a1, bb[fc], acc[1][fc], 0, 0, 0);
            }
        }
    }
    #pragma unroll
    for (int fr = 0; fr < 2; ++fr)
        #pragma unroll
        for (int fc = 0; fc < 4; ++fc)
            #pragma unroll
            for (int reg = 0; reg < 4; ++reg) {
                int i = i0 + w * 32 + fr * 16 + (lane >> 4) * 4 + reg;
                int d = fc * 16 + l15;
                float v = acc[fr][fc][reg];
                size_t oo = ((size_t)b * S_ + i) * Z_ + d;
                if (fp32) outF[oo] = v;
                else      outB[oo] = f2bf(v);
            }
}

// ---------------------------------------------------------------------------
// K3-fallback (only when !use_stage): fused scale+AV.
// ---------------------------------------------------------------------------
__global__ __launch_bounds__(256, 2) void av_fallback_kernel(
        const u16* __restrict__ vT, const float* __restrict__ scl,
        u16* __restrict__ attnB, float* __restrict__ attnF,
        u16* __restrict__ outB, float* __restrict__ outF,
        const int* __restrict__ flagp)
{
    __shared__ __align__(16) u16 lds_attn[128 * 128];
    __shared__ __align__(16) u16 lds_vt[64 * 128];
    __shared__ float lds_scale[128];
    const int fp32 = *flagp;
    const int t = threadIdx.x;
    const int lane = t & 63, w = t >> 6;
    const int it = blockIdx.x, b = blockIdx.y;
    const int i0 = it * 128;
    const int l15 = lane & 15, koff = (lane >> 4) * 8;
    const size_t sclbase = ((size_t)b * NIT_ + (it >> 1)) * S_;

    f32x4 acc[2][4];
    #pragma unroll
    for (int a = 0; a < 2; ++a)
        #pragma unroll
        for (int c = 0; c < 4; ++c) acc[a][c] = (f32x4){0.f, 0.f, 0.f, 0.f};

    for (int jt = 0; jt < 16; ++jt) {
        const int j0 = jt * 128;
        __syncthreads();
        if (t < 128) lds_scale[t] = scl[sclbase + j0 + t];
        #pragma unroll
        for (int rep = 0; rep < 4; ++rep) {
            int s = t + rep * 256;
            int d = s >> 4, off = (s & 15) * 8;
            gl2lds16(vT + ((size_t)b * 64 + d) * S_ + j0 + off, lds_vt + s * 8);
        }
        __syncthreads();

        const size_t abase = ((size_t)b * S_ + i0) * S_ + j0;
        if (fp32) {
            #pragma unroll
            for (int rep = 0; rep < 8; ++rep) {
                int s = t + rep * 256;
                int row = s >> 4, off = (s & 15) * 8;
                float* gp = attnF + abase + (size_t)row * S_ + off;
                float4 p0 = *(const float4*)gp;
                float4 p1 = *(const float4*)(gp + 4);
                p0.x *= lds_scale[off + 0]; p0.y *= lds_scale[off + 1];
                p0.z *= lds_scale[off + 2]; p0.w *= lds_scale[off + 3];
                p1.x *= lds_scale[off + 4]; p1.y *= lds_scale[off + 5];
                p1.z *= lds_scale[off + 6]; p1.w *= lds_scale[off + 7];
                *(float4*)gp = p0;
                *(float4*)(gp + 4) = p1;
                uint4 pk;
                pk.x = (unsigned)f2bf(p0.x) | ((unsigned)f2bf(p0.y) << 16);
                pk.y = (unsigned)f2bf(p0.z) | ((unsigned)f2bf(p0.w) << 16);
                pk.z = (unsigned)f2bf(p1.x) | ((unsigned)f2bf(p1.y) << 16);
                pk.w = (unsigned)f2bf(p1.z) | ((unsigned)f2bf(p1.w) << 16);
                *(uint4*)(lds_attn + s * 8) = pk;
            }
        } else {
            #pragma unroll
            for (int rep = 0; rep < 8; ++rep) {
                int s = t + rep * 256;
                int row = s >> 4, off = (s & 15) * 8;
                size_t ga = abase + (size_t)row * S_ + off;
                uint4 pk = *(const uint4*)(attnB + ga);
                unsigned int wd[4] = {pk.x, pk.y, pk.z, pk.w};
                #pragma unroll
                for (int e2 = 0; e2 < 4; ++e2) {
                    float f0 = bf2f((u16)(wd[e2] & 0xffffu)) * lds_scale[off + e2 * 2];
                    float f1 = bf2f((u16)(wd[e2] >> 16))     * lds_scale[off + e2 * 2 + 1];
                    wd[e2] = (unsigned int)f2bf(f0) | ((unsigned int)f2bf(f1) << 16);
                }
                uint4 opk; opk.x = wd[0]; opk.y = wd[1]; opk.z = wd[2]; opk.w = wd[3];
                *(uint4*)(attnB + ga) = opk;
                *(uint4*)(lds_attn + s * 8) = opk;
            }
        }
        __syncthreads();

        #pragma unroll
        for (int ksj = 0; ksj < 4; ++ksj) {
            bf16x8 a0 = *(const bf16x8*)(lds_attn + (w * 32 +  0 + l15) * 128 + ksj * 32 + koff);
            bf16x8 a1 = *(const bf16x8*)(lds_attn + (w * 32 + 16 + l15) * 128 + ksj * 32 + koff);
            bf16x8 bb[4];
            #pragma unroll
            for (int fc = 0; fc < 4; ++fc)
                bb[fc] = *(const bf16x8*)(lds_vt + (fc * 16 + l15) * 128 + ksj * 32 + koff);
            #pragma unroll
            for (int fc = 0; fc < 4; ++fc) {
                acc[0][fc] = __builtin_amdgcn_mfma_f32_16x16x32_bf16(a0, bb[fc], acc[0][fc], 0, 0, 0);
                acc[1][fc] = __builtin_amdgcn_mfma_f32_16x16x32_bf16(a1, bb[fc], acc[1][fc], 0, 0, 0);
            }
        }
    }
    #pragma unroll
    for (int fr = 0; fr < 2; ++fr)
        #pragma unroll
        for (int fc = 0; fc < 4; ++fc)
            #pragma unroll
            for (int reg = 0; reg < 4; ++reg) {
                int i = i0 + w * 32 + fr * 16 + (lane >> 4) * 4 + reg;
                int d = fc * 16 + l15;
                float v = acc[fr][fc][reg];
                size_t oo = ((size_t)b * S_ + i) * Z_ + d;
                if (fp32) outF[oo] = v;
                else      outB[oo] = f2bf(v);
            }
}

// ---------------------------------------------------------------------------
extern "C" void kernel_launch(void* const* d_in, const int* in_sizes, int n_in,
                              void* d_out, int out_size, void* d_ws, size_t ws_size,
                              hipStream_t stream) {
    const void* enc    = d_in[0];
    const void* dec    = d_in[1];
    const void* latent = d_in[3];
    const void* mraw   = d_in[4];
    const void* Wq     = d_in[5];
    const void* Wk     = d_in[6];
    const void* Wv     = d_in[7];

    u16*   outB  = (u16*)d_out;
    float* outF  = (float*)d_out;
    u16*   attnB = outB + (size_t)B_ * S_ * Z_;
    float* attnF = outF + (size_t)B_ * S_ * Z_;
    float* m_p = (float*)d_out;                    // dead-until-av output0 head
    float* s_p = m_p + (size_t)B_ * NIT_ * S_;     // 2+2 MB <= output0 region

    char* ws = (char*)d_ws;
    int*   flag  = (int*)ws;                                       // 256 B slot
    int*   maskI = (int*)(ws + 256);                               // 256 KB
    u16*   vT    = (u16*)((char*)maskI + (size_t)B_ * S_ * 4);     // 8 MB
    u16*   WqTh  = vT + (size_t)B_ * Z_ * S_;                      // 6 x 128 KB
    u16*   WqTl  = WqTh + H_ * H_;
    u16*   WkTh  = WqTl + H_ * H_;
    u16*   WkTl  = WkTh + H_ * H_;
    u16*   Gh    = WkTl + H_ * H_;
    u16*   Gl    = Gh + H_ * H_;
    float* scl   = (float*)(Gl + H_ * H_);                         // 2 MB
    char*  dyn   = (char*)(scl + (size_t)B_ * NIT_ * S_);

    const size_t fixed_bytes  = (size_t)(dyn - ws);                // ~11 MB
    const size_t per_batch    = (size_t)4 * S_ * H_ * 2;           // 4 MB
    const size_t xsplit_bytes = (size_t)4 * B_ * S_ * H_ * 2;      // 128 MB
    const size_t stage_bytes  = (size_t)B_ * S_ * S_ * 2;          // 256 MB

    long long avail = (long long)ws_size - (long long)fixed_bytes;
    int use_xsplit = 0, use_stage = 0;
    u16 *Xdh = 0, *Xdl = 0, *Xeh = 0, *Xel = 0, *stageB = 0;
    if (avail >= (long long)(xsplit_bytes + per_batch)) {
        use_xsplit = 1;
        Xdh = (u16*)dyn;
        Xdl = Xdh + (size_t)B_ * S_ * H_;
        Xeh = Xdl + (size_t)B_ * S_ * H_;
        Xel = Xeh + (size_t)B_ * S_ * H_;
        dyn += xsplit_bytes;
        avail -= (long long)xsplit_bytes;
    }
    if (avail >= (long long)(stage_bytes + per_batch)) {
        use_stage = 1;
        stageB = (u16*)dyn;
        dyn += stage_bytes;
        avail -= (long long)stage_bytes;
    }
    int g_b = (avail > 0) ? (int)(avail / (long long)per_batch) : 1;
    if (g_b < 1)  g_b = 1;
    if (g_b > 32) g_b = 32;

    u16* qh = (u16*)dyn;
    u16* ql = qh + (size_t)g_b * S_ * H_;
    u16* kh = ql + (size_t)g_b * S_ * H_;
    u16* kl = kh + (size_t)g_b * S_ * H_;

    detect_kernel<<<dim3(1), 256, 0, stream>>>((const u16*)Wq, flag);

    const int n_xs = use_xsplit ? 8192 : 0;
    prep_kernel<<<dim3(n_xs + 1024 + 128 + 256 + 256), 256, 0, stream>>>(
        flag, n_xs, dec, enc, Xdh, Xdl, Xeh, Xel,
        latent, Wv, vT, Wq, Wk, WqTh, WqTl, WkTh, WkTl, Gh, Gl, mraw, maskI);

    for (int b0 = 0; b0 < B_; b0 += g_b) {
        int g = (B_ - b0 < g_b) ? (B_ - b0) : g_b;
        size_t eoff = (size_t)b0 * S_ * H_;   // element offset, dtype-agnostic
        if (use_xsplit) {
            // G-path: q = dec (pre-split); only k' = enc @ G^T projected.
            proj_kernel<<<dim3(g * 16, 2, 1), 256, 0, stream>>>(
                flag, use_xsplit,
                (const float*)enc + eoff, (const u16*)enc + eoff,
                Xeh + eoff, Xel + eoff,
                Gh, Gl, kh, kl,
                (const float*)enc + eoff, (const u16*)enc + eoff,
                Xeh + eoff, Xel + eoff,
                Gh, Gl, kh, kl);
            qk_kernel<<<dim3(NIT_, NIT_, g), 512, 0, stream>>>(
                Xdh + eoff, Xdl + eoff, kh, kl, maskI,
                attnB, attnF, stageB, use_stage, m_p, s_p, b0, flag);
        } else {
            proj_kernel<<<dim3(g * 16, 2, 2), 256, 0, stream>>>(
                flag, use_xsplit,
                (const float*)dec + eoff, (const u16*)dec + eoff,
                (u16*)0, (u16*)0, WqTh, WqTl, qh, ql,
                (const float*)enc + eoff, (const u16*)enc + eoff,
                (u16*)0, (u16*)0, WkTh, WkTl, kh, kl);
            qk_kernel<<<dim3(NIT_, NIT_, g), 512, 0, stream>>>(
                qh, ql, kh, kl, maskI,
                attnB, attnF, stageB, use_stage, m_p, s_p, b0, flag);
        }
    }
    stats_kernel<<<dim3(256), 256, 0, stream>>>(m_p, s_p, scl);
    if (use_stage) {
        av_gemm_kernel<<<dim3(16, 32), 256, 0, stream>>>(vT, scl, stageB, attnB, attnF,
                                                         outB, outF, flag);
    } else {
        av_fallback_kernel<<<dim3(16, 32), 256, 0, stream>>>(vT, scl, attnB, attnF,
                                                             outB, outF, flag);
    }
}

// Round 6
// 1089.325 us; speedup vs baseline: 1.1999x; 1.1999x over previous
//
#include <hip/hip_runtime.h>
#include <stdint.h>

// Problem dims (fixed)
#define B_  32
#define S_  2048
#define H_  256
#define Z_  64
#define NIT_ 16

typedef unsigned short u16;
typedef __attribute__((ext_vector_type(8))) short bf16x8;   // 8 bf16 in 4 VGPRs
typedef __attribute__((ext_vector_type(4))) float f32x4;

__device__ __forceinline__ u16 f2bf(float f) {
    unsigned int x = __float_as_uint(f);
    x = (x + 0x7fffu + ((x >> 16) & 1u)) >> 16;   // RNE
    return (u16)x;
}
__device__ __forceinline__ float bf2f(u16 u) {
    return __uint_as_float(((unsigned int)u) << 16);
}

// async global->LDS, 16B per lane. LDS dest is wave-uniform base + lane*16.
__device__ __forceinline__ void gl2lds16(const void* g, void* l) {
    __builtin_amdgcn_global_load_lds(
        (const __attribute__((address_space(1))) unsigned int*)g,
        (__attribute__((address_space(3))) unsigned int*)l,
        16, 0, 0);
}

// ---------------------------------------------------------------------------
// K_detect: fp32 (flag=1) vs bf16 (flag=0) from Wq's even-indexed u16s.
// ---------------------------------------------------------------------------
__global__ void detect_kernel(const u16* __restrict__ wq, int* __restrict__ flag) {
    __shared__ int tot;
    const int t = threadIdx.x;
    if (t == 0) tot = 0;
    __syncthreads();
    int cnt = 0;
    #pragma unroll
    for (int r = 0; r < 16; ++r) {
        u16 u = wq[(r * 256 + t) * 2];
        int e = (u >> 7) & 0xFF;
        cnt += (u == 0 || (e >= 107 && e <= 132)) ? 1 : 0;
    }
    atomicAdd(&tot, cnt);
    __syncthreads();
    if (t == 0) *flag = (tot < 2048) ? 1 : 0;    // 1 = fp32 inputs
}

// ---------------------------------------------------------------------------
// prep roles (device bodies) — fused into one dispatch.
// ---------------------------------------------------------------------------
__device__ void role_mask(int bx, const void* __restrict__ raw, int* __restrict__ mi) {
    __shared__ int isByte;
    const int t = threadIdx.x;
    if (t == 0) isByte = 0;
    __syncthreads();
    const unsigned int* w = (const unsigned int*)raw;
    if (w[t & 255] > 1u) isByte = 1;
    __syncthreads();
    int e = bx * 256 + t;
    int val;
    if (isByte) val = ((const unsigned char*)raw)[e] ? 1 : 0;
    else        val = w[e] ? 1 : 0;
    mi[e] = val;
}

__device__ void role_wsplit(int bx, int by, int fp32,
                            const void* __restrict__ Wq, const void* __restrict__ Wk,
                            u16* __restrict__ WqTh, u16* __restrict__ WqTl,
                            u16* __restrict__ WkTh, u16* __restrict__ WkTl) {
    const void* src = by ? Wk : Wq;
    u16* oh = by ? WkTh : WqTh;
    u16* ol = by ? WkTl : WqTl;
    int base = bx * 1024;
    #pragma unroll
    for (int r = 0; r < 4; ++r) {
        int idx = base + r * 256 + threadIdx.x;
        int d = idx >> 8, h = idx & 255;
        float v = fp32 ? ((const float*)src)[h * 256 + d]
                       : bf2f(((const u16*)src)[h * 256 + d]);
        u16 hi = f2bf(v);
        oh[idx] = hi;
        ol[idx] = f2bf(v - bf2f(hi));
    }
}

// G[d][h] = sum_e Wq[d,e] * Wk[h,e]  (fp32), split hi/lo.
// Transposed weight for k' = enc @ G^T; then alignment = dec . k'^T.
__device__ void role_gmat(int d, int fp32,
                          const void* __restrict__ Wq, const void* __restrict__ Wk,
                          u16* __restrict__ Gh, u16* __restrict__ Gl) {
    __shared__ float wqrow[256];
    const int t = threadIdx.x;
    wqrow[t] = fp32 ? ((const float*)Wq)[d * 256 + t]
                    : bf2f(((const u16*)Wq)[d * 256 + t]);
    __syncthreads();
    float s = 0.f;
    if (fp32) {
        const float* wk = (const float*)Wk + (size_t)t * 256;
        for (int e = 0; e < 256; ++e) s += wqrow[e] * wk[e];
    } else {
        const u16* wk = (const u16*)Wk + (size_t)t * 256;
        for (int e = 0; e < 256; ++e) s += wqrow[e] * bf2f(wk[e]);
    }
    u16 hi = f2bf(s);
    Gh[d * 256 + t] = hi;
    Gl[d * 256 + t] = f2bf(s - bf2f(hi));
}

__device__ void role_xsplit(int bx, int by, int fp32,
                            const void* __restrict__ dec, const void* __restrict__ enc,
                            u16* __restrict__ Xdh, u16* __restrict__ Xdl,
                            u16* __restrict__ Xeh, u16* __restrict__ Xel) {
    const void* src = by ? enc : dec;
    u16* oh = by ? Xeh : Xdh;
    u16* ol = by ? Xel : Xdl;
    const int t = threadIdx.x;
    const size_t blockbase = (size_t)bx * 4096;
    if (fp32) {
        const float4* s4 = (const float4*)src;
        #pragma unroll
        for (int j = 0; j < 4; ++j) {
            size_t idx = blockbase + j * 1024 + t * 4;
            float4 v = s4[idx >> 2];
            u16 h0 = f2bf(v.x), h1 = f2bf(v.y), h2 = f2bf(v.z), h3 = f2bf(v.w);
            u16 l0 = f2bf(v.x - bf2f(h0)), l1 = f2bf(v.y - bf2f(h1));
            u16 l2 = f2bf(v.z - bf2f(h2)), l3 = f2bf(v.w - bf2f(h3));
            uint2 ph, pl;
            ph.x = (unsigned)h0 | ((unsigned)h1 << 16);
            ph.y = (unsigned)h2 | ((unsigned)h3 << 16);
            pl.x = (unsigned)l0 | ((unsigned)l1 << 16);
            pl.y = (unsigned)l2 | ((unsigned)l3 << 16);
            ((uint2*)oh)[idx >> 2] = ph;
            ((uint2*)ol)[idx >> 2] = pl;
        }
    } else {
        const uint2* s2 = (const uint2*)src;
        #pragma unroll
        for (int j = 0; j < 4; ++j) {
            size_t idx = blockbase + j * 1024 + t * 4;
            uint2 r = s2[idx >> 2];
            uint2 z; z.x = 0u; z.y = 0u;
            ((uint2*)oh)[idx >> 2] = r;
            ((uint2*)ol)[idx >> 2] = z;
        }
    }
}

__device__ void role_vproj(int bx, int dc, int fp32,
                           const void* __restrict__ Lraw,
                           const void* __restrict__ Wvraw, u16* __restrict__ vT) {
    __shared__ float wv[64 * 16];
    const int t = threadIdx.x;
    #pragma unroll
    for (int r = 0; r < 4; ++r) {
        int idx = r * 256 + t;
        int z = idx >> 4, dd = idx & 15;
        wv[idx] = fp32 ? ((const float*)Wvraw)[z * 64 + dc * 16 + dd]
                       : bf2f(((const u16*)Wvraw)[z * 64 + dc * 16 + dd]);
    }
    __syncthreads();
    const int flat = bx * 256 + t;
    const int b = flat >> 11, s = flat & 2047;

    float lz[64];
    if (fp32) {
        const float4* lr = (const float4*)((const float*)Lraw + (size_t)flat * 64);
        #pragma unroll
        for (int c = 0; c < 16; ++c) {
            float4 v = lr[c];
            lz[c * 4 + 0] = v.x; lz[c * 4 + 1] = v.y;
            lz[c * 4 + 2] = v.z; lz[c * 4 + 3] = v.w;
        }
    } else {
        const uint4* lr = (const uint4*)((const u16*)Lraw + (size_t)flat * 64);
        #pragma unroll
        for (int c = 0; c < 8; ++c) {
            uint4 v = lr[c];
            unsigned wd[4] = {v.x, v.y, v.z, v.w};
            #pragma unroll
            for (int e2 = 0; e2 < 4; ++e2) {
                lz[c * 8 + e2 * 2 + 0] = bf2f((u16)(wd[e2] & 0xffffu));
                lz[c * 8 + e2 * 2 + 1] = bf2f((u16)(wd[e2] >> 16));
            }
        }
    }

    float acc[16];
    #pragma unroll
    for (int d = 0; d < 16; ++d) acc[d] = 0.f;
    for (int z = 0; z < 64; ++z) {
        float lv = lz[z];
        const float4* wrow = (const float4*)&wv[z * 16];
        #pragma unroll
        for (int d4 = 0; d4 < 4; ++d4) {
            float4 wq = wrow[d4];
            acc[d4 * 4 + 0] += lv * wq.x;
            acc[d4 * 4 + 1] += lv * wq.y;
            acc[d4 * 4 + 2] += lv * wq.z;
            acc[d4 * 4 + 3] += lv * wq.w;
        }
    }
    #pragma unroll
    for (int d = 0; d < 16; ++d)
        vT[((size_t)b * 64 + dc * 16 + d) * S_ + s] = f2bf(acc[d]);
}

// One dispatch for all prep work. Block ranges: [0,n_xs) xsplit,
// then 1024 vproj, then 128 wsplit, then 256 mask, then 256 gmat.
__global__ __launch_bounds__(256) void prep_kernel(
        const int* __restrict__ flagp, int n_xs,
        const void* __restrict__ dec, const void* __restrict__ enc,
        u16* __restrict__ Xdh, u16* __restrict__ Xdl,
        u16* __restrict__ Xeh, u16* __restrict__ Xel,
        const void* __restrict__ Lraw, const void* __restrict__ Wvraw,
        u16* __restrict__ vT,
        const void* __restrict__ Wq, const void* __restrict__ Wk,
        u16* __restrict__ WqTh, u16* __restrict__ WqTl,
        u16* __restrict__ WkTh, u16* __restrict__ WkTl,
        u16* __restrict__ Gh, u16* __restrict__ Gl,
        const void* __restrict__ mraw, int* __restrict__ maskI)
{
    const int fp32 = *flagp;
    int r = blockIdx.x;
    if (r < n_xs) {
        role_xsplit(r & 4095, r >> 12, fp32, dec, enc, Xdh, Xdl, Xeh, Xel);
        return;
    }
    r -= n_xs;
    if (r < 1024) {
        role_vproj(r & 255, r >> 8, fp32, Lraw, Wvraw, vT);
        return;
    }
    r -= 1024;
    if (r < 128) {
        role_wsplit(r & 63, r >> 6, fp32, Wq, Wk, WqTh, WqTl, WkTh, WkTl);
        return;
    }
    r -= 128;
    if (r < 256) {
        role_mask(r, mraw, maskI);
        return;
    }
    r -= 256;
    role_gmat(r, fp32, Wq, Wk, Gh, Gl);
}

// ---------------------------------------------------------------------------
// K0: P = X @ W via 3-product split (single-buffer, R3 structure).
// blockIdx.z selects problem set; XOR-swizzled staging (pos = chunk ^ (row&7)).
// ---------------------------------------------------------------------------
__global__ __launch_bounds__(256, 2) void proj_kernel(
        const int* __restrict__ flagp, int use_xsplit,
        const float* __restrict__ Xf0, const u16* __restrict__ Xu0,
        const u16* __restrict__ Xh0, const u16* __restrict__ Xl0,
        const u16* __restrict__ WTh0, const u16* __restrict__ WTl0,
        u16* __restrict__ Ph0, u16* __restrict__ Pl0,
        const float* __restrict__ Xf1, const u16* __restrict__ Xu1,
        const u16* __restrict__ Xh1, const u16* __restrict__ Xl1,
        const u16* __restrict__ WTh1, const u16* __restrict__ WTl1,
        u16* __restrict__ Ph1, u16* __restrict__ Pl1)
{
    __shared__ __align__(16) u16 lds[16384];   // A slab [0,8192) u16, B slab [8192,16384)
    const int z = blockIdx.z;
    const float* Xf = z ? Xf1 : Xf0;
    const u16*   Xu = z ? Xu1 : Xu0;
    const u16*   Xh = z ? Xh1 : Xh0;
    const u16*   Xl = z ? Xl1 : Xl0;
    const u16*  WTh = z ? WTh1 : WTh0;
    const u16*  WTl = z ? WTl1 : WTl0;
    u16* Ph = z ? Ph1 : Ph0;
    u16* Pl = z ? Pl1 : Pl0;

    const int fp32 = *flagp;
    const int t = threadIdx.x;
    const int lane = t & 63, w = t >> 6;
    const int i0 = blockIdx.x * 128;
    const int d0 = blockIdx.y * 128;
    const int rh = w >> 1, ch = w & 1;
    const int l15 = lane & 15;
    const int c0 = lane >> 4;                 // fragment chunk (0..3)

    const int srow = t >> 3;                  // base row (rep adds 32)
    const int scp  = t & 7;                   // chunk position in row
    const int sc   = scp ^ (srow & 7);        // logical chunk held there
    const int scol = (sc & 3) * 8;            // k-col offset within 32
    const int slo  = sc & 4;                  // lo half?

    f32x4 acc[4][4];
    #pragma unroll
    for (int a = 0; a < 4; ++a)
        #pragma unroll
        for (int c = 0; c < 4; ++c) acc[a][c] = (f32x4){0.f, 0.f, 0.f, 0.f};

    for (int ks = 0; ks < 8; ++ks) {
        const int kc = ks * 32;
        {
            const u16* wsrc = slo ? WTl : WTh;
            #pragma unroll
            for (int rep = 0; rep < 4; ++rep) {
                int s = t + rep * 256;        // 0..1023
                int row = srow + rep * 32;
                gl2lds16(wsrc + (size_t)(d0 + row) * H_ + kc + scol, lds + 8192 + s * 8);
            }
        }
        if (use_xsplit) {
            const u16* xsrc = slo ? Xl : Xh;
            #pragma unroll
            for (int rep = 0; rep < 4; ++rep) {
                int s = t + rep * 256;
                int row = srow + rep * 32;
                gl2lds16(xsrc + (size_t)(i0 + row) * H_ + kc + scol, lds + s * 8);
            }
        } else if (fp32) {
            #pragma unroll
            for (int rep = 0; rep < 2; ++rep) {
                int s = t + rep * 256;
                int r = s >> 2, c8 = s & 3;
                const float4* src = (const float4*)(Xf + (size_t)(i0 + r) * H_ + kc + c8 * 8);
                float4 x0 = src[0], x1 = src[1];
                float xs[8] = {x0.x, x0.y, x0.z, x0.w, x1.x, x1.y, x1.z, x1.w};
                unsigned hh[8], ll[8];
                #pragma unroll
                for (int j = 0; j < 8; ++j) {
                    u16 hb = f2bf(xs[j]);
                    hh[j] = hb;
                    ll[j] = f2bf(xs[j] - bf2f(hb));
                }
                uint4 ph, pl;
                ph.x = hh[0] | (hh[1] << 16); ph.y = hh[2] | (hh[3] << 16);
                ph.z = hh[4] | (hh[5] << 16); ph.w = hh[6] | (hh[7] << 16);
                pl.x = ll[0] | (ll[1] << 16); pl.y = ll[2] | (ll[3] << 16);
                pl.z = ll[4] | (ll[5] << 16); pl.w = ll[6] | (ll[7] << 16);
                int posH = c8 ^ (r & 7);
                *(uint4*)(lds + r * 64 + posH * 8) = ph;
                *(uint4*)(lds + r * 64 + (posH ^ 4) * 8) = pl;
            }
        } else {
            #pragma unroll
            for (int rep = 0; rep < 2; ++rep) {
                int s = t + rep * 256;
                int r = s >> 2, c8 = s & 3;
                uint4 raw = *(const uint4*)(Xu + (size_t)(i0 + r) * H_ + kc + c8 * 8);
                int posH = c8 ^ (r & 7);
                *(uint4*)(lds + r * 64 + posH * 8) = raw;
                *(uint4*)(lds + r * 64 + (posH ^ 4) * 8) = (uint4){0u, 0u, 0u, 0u};
            }
        }
        __syncthreads();
        bf16x8 ah[4], al[4], bh[4], bl[4];
        #pragma unroll
        for (int f = 0; f < 4; ++f) {
            int ra = rh * 64 + f * 16 + l15;
            int rb = ch * 64 + f * 16 + l15;
            int pa = c0 ^ (ra & 7);
            int pb = c0 ^ (rb & 7);
            ah[f] = *(const bf16x8*)(lds + ra * 64 + pa * 8);
            al[f] = *(const bf16x8*)(lds + ra * 64 + (pa ^ 4) * 8);
            bh[f] = *(const bf16x8*)(lds + 8192 + rb * 64 + pb * 8);
            bl[f] = *(const bf16x8*)(lds + 8192 + rb * 64 + (pb ^ 4) * 8);
        }
        #pragma unroll
        for (int fr = 0; fr < 4; ++fr)
            #pragma unroll
            for (int fc = 0; fc < 4; ++fc) {
                acc[fr][fc] = __builtin_amdgcn_mfma_f32_16x16x32_bf16(al[fr], bh[fc], acc[fr][fc], 0, 0, 0);
                acc[fr][fc] = __builtin_amdgcn_mfma_f32_16x16x32_bf16(ah[fr], bl[fc], acc[fr][fc], 0, 0, 0);
                acc[fr][fc] = __builtin_amdgcn_mfma_f32_16x16x32_bf16(ah[fr], bh[fc], acc[fr][fc], 0, 0, 0);
            }
        __syncthreads();
    }
    #pragma unroll
    for (int fr = 0; fr < 4; ++fr)
        #pragma unroll
        for (int fc = 0; fc < 4; ++fc)
            #pragma unroll
            for (int reg = 0; reg < 4; ++reg) {
                float v = acc[fr][fc][reg];
                int i = i0 + rh * 64 + fr * 16 + (lane >> 4) * 4 + reg;
                int d = d0 + ch * 64 + fc * 16 + l15;
                u16 hi = f2bf(v);
                u16 lo = f2bf(v - bf2f(hi));
                size_t off = (size_t)i * H_ + d;
                Ph[off] = hi;
                Pl[off] = lo;
            }
}

// ---------------------------------------------------------------------------
// K1: logits via 3-product split; XOR-swizzled staging (R3-proven 128² form).
// ---------------------------------------------------------------------------
__global__ __launch_bounds__(256, 2) void qk_kernel(
        const u16* __restrict__ qh, const u16* __restrict__ ql,
        const u16* __restrict__ kh, const u16* __restrict__ kl,
        const int* __restrict__ maskI, u16* __restrict__ attnB,
        float* __restrict__ attnF, u16* __restrict__ stageB, int use_stage,
        float* __restrict__ m_p, float* __restrict__ s_p,
        int b0, const int* __restrict__ flagp)
{
    __shared__ __align__(16) char smem[35328];
    u16*  stage = (u16*)smem;
    u16*  etile = (u16*)smem;
    float* cmax = (float*)(smem + 32768);
    float* csum = (float*)(smem + 33792);
    float* mrow = (float*)(smem + 34816);

    const int fp32 = *flagp;
    const int t = threadIdx.x;
    const int lane = t & 63, w = t >> 6;
    const int jt = blockIdx.x, it = blockIdx.y, bz = blockIdx.z;
    const int b = b0 + bz;
    const int i0 = it * 128, j0 = jt * 128;
    const int rh = w >> 1, ch = w & 1;
    const int l15 = lane & 15;
    const int c0 = lane >> 4;

    if (t < 128) mrow[t] = (maskI[b * S_ + i0 + t] != 0) ? 1.f : 0.f;

    const size_t qbase = ((size_t)bz * S_ + i0) * H_;
    const size_t kbase = ((size_t)bz * S_ + j0) * H_;

    const int srow = t >> 3;
    const int scp  = t & 7;
    const int sc   = scp ^ (srow & 7);
    const int scol = (sc & 3) * 8;
    const u16* qsrc = (sc & 4) ? ql : qh;
    const u16* ksrc = (sc & 4) ? kl : kh;

    f32x4 acc[4][4];
    #pragma unroll
    for (int a = 0; a < 4; ++a)
        #pragma unroll
        for (int c = 0; c < 4; ++c) acc[a][c] = (f32x4){0.f, 0.f, 0.f, 0.f};

    for (int ks = 0; ks < 8; ++ks) {
        const int kc = ks * 32;
        #pragma unroll
        for (int rep = 0; rep < 4; ++rep) {
            int s = t + rep * 256;
            int row = srow + rep * 32;
            gl2lds16(qsrc + qbase + (size_t)row * H_ + kc + scol, stage + s * 8);
            gl2lds16(ksrc + kbase + (size_t)row * H_ + kc + scol, stage + 8192 + s * 8);
        }
        __syncthreads();
        bf16x8 ah[4], al[4], bh[4], bl[4];
        #pragma unroll
        for (int f = 0; f < 4; ++f) {
            int ra = rh * 64 + f * 16 + l15;
            int rb = ch * 64 + f * 16 + l15;
            int pa = c0 ^ (ra & 7);
            int pb = c0 ^ (rb & 7);
            ah[f] = *(const bf16x8*)(stage + ra * 64 + pa * 8);
            al[f] = *(const bf16x8*)(stage + ra * 64 + (pa ^ 4) * 8);
            bh[f] = *(const bf16x8*)(stage + 8192 + rb * 64 + pb * 8);
            bl[f] = *(const bf16x8*)(stage + 8192 + rb * 64 + (pb ^ 4) * 8);
        }
        #pragma unroll
        for (int fr = 0; fr < 4; ++fr)
            #pragma unroll
            for (int fc = 0; fc < 4; ++fc) {
                acc[fr][fc] = __builtin_amdgcn_mfma_f32_16x16x32_bf16(al[fr], bh[fc], acc[fr][fc], 0, 0, 0);
                acc[fr][fc] = __builtin_amdgcn_mfma_f32_16x16x32_bf16(ah[fr], bl[fc], acc[fr][fc], 0, 0, 0);
                acc[fr][fc] = __builtin_amdgcn_mfma_f32_16x16x32_bf16(ah[fr], bh[fc], acc[fr][fc], 0, 0, 0);
            }
        __syncthreads();
    }

    const float inv_t = 0.0625f;
    float mloc[4] = {-3e38f, -3e38f, -3e38f, -3e38f};
    #pragma unroll
    for (int fr = 0; fr < 4; ++fr)
        #pragma unroll
        for (int reg = 0; reg < 4; ++reg) {
            float keep = mrow[rh * 64 + fr * 16 + (lane >> 4) * 4 + reg];
            #pragma unroll
            for (int fc = 0; fc < 4; ++fc) {
                float l = acc[fr][fc][reg] * inv_t;
                l = (keep != 0.f) ? l : -1e9f;
                acc[fr][fc][reg] = l;
                mloc[fc] = fmaxf(mloc[fc], l);
            }
        }
    #pragma unroll
    for (int fc = 0; fc < 4; ++fc) {
        mloc[fc] = fmaxf(mloc[fc], __shfl_xor(mloc[fc], 16, 64));
        mloc[fc] = fmaxf(mloc[fc], __shfl_xor(mloc[fc], 32, 64));
    }
    if (lane < 16) {
        #pragma unroll
        for (int fc = 0; fc < 4; ++fc)
            cmax[rh * 128 + ch * 64 + fc * 16 + lane] = mloc[fc];
    }
    __syncthreads();

    float mcol[4], sloc[4];
    #pragma unroll
    for (int fc = 0; fc < 4; ++fc) {
        int c = ch * 64 + fc * 16 + l15;
        mcol[fc] = fmaxf(cmax[c], cmax[128 + c]);
        sloc[fc] = 0.f;
    }
    #pragma unroll
    for (int fr = 0; fr < 4; ++fr)
        #pragma unroll
        for (int reg = 0; reg < 4; ++reg) {
            int row = rh * 64 + fr * 16 + (lane >> 4) * 4 + reg;
            #pragma unroll
            for (int fc = 0; fc < 4; ++fc) {
                float e = __expf(acc[fr][fc][reg] - mcol[fc]);
                sloc[fc] += e;
                etile[row * 128 + ch * 64 + fc * 16 + l15] = f2bf(e);
            }
        }
    #pragma unroll
    for (int fc = 0; fc < 4; ++fc) {
        sloc[fc] += __shfl_xor(sloc[fc], 16, 64);
        sloc[fc] += __shfl_xor(sloc[fc], 32, 64);
    }
    if (lane < 16) {
        #pragma unroll
        for (int fc = 0; fc < 4; ++fc)
            csum[rh * 128 + ch * 64 + fc * 16 + lane] = sloc[fc];
    }
    __syncthreads();

    if (t < 128) {
        float m = fmaxf(cmax[t], cmax[128 + t]);
        float sres = csum[t] + csum[128 + t];
        size_t so = ((size_t)b * NIT_ + it) * S_ + j0 + t;
        m_p[so] = m;
        s_p[so] = sres;
    }
    const size_t abase = ((size_t)b * S_ + i0) * S_ + j0;
    if (fp32) {
        if (use_stage) {
            #pragma unroll
            for (int rep = 0; rep < 8; ++rep) {
                int s = t + rep * 256;
                int row = s >> 4, off = (s & 15) * 8;
                *(uint4*)(stageB + abase + (size_t)row * S_ + off) = *(const uint4*)(etile + s * 8);
            }
        } else {
            #pragma unroll
            for (int rep = 0; rep < 8; ++rep) {
                int s = t + rep * 256;
                int row = s >> 4, off = (s & 15) * 8;
                const u16* src = etile + s * 8;
                float* gp = attnF + abase + (size_t)row * S_ + off;
                float4 f0, f1;
                f0.x = bf2f(src[0]); f0.y = bf2f(src[1]); f0.z = bf2f(src[2]); f0.w = bf2f(src[3]);
                f1.x = bf2f(src[4]); f1.y = bf2f(src[5]); f1.z = bf2f(src[6]); f1.w = bf2f(src[7]);
                *(float4*)gp = f0;
                *(float4*)(gp + 4) = f1;
            }
        }
    } else {
        #pragma unroll
        for (int rep = 0; rep < 8; ++rep) {
            int s = t + rep * 256;
            int row = s >> 4, off = (s & 15) * 8;
            *(uint4*)(attnB + abase + (size_t)row * S_ + off) = *(const uint4*)(etile + s * 8);
        }
    }
}

// ---------------------------------------------------------------------------
// K2: scale[b][it][j] = exp(m_p - M) / L   (NIT_=16 i-tiles of 128 rows)
// ---------------------------------------------------------------------------
__global__ __launch_bounds__(256) void stats_kernel(
        const float* __restrict__ m_p, const float* __restrict__ s_p, float* __restrict__ scl)
{
    int id = blockIdx.x * 256 + threadIdx.x;
    int b = id >> 11, j = id & 2047;
    float mv[NIT_];
    float M = -3e38f;
    #pragma unroll
    for (int itile = 0; itile < NIT_; ++itile) {
        mv[itile] = m_p[((size_t)b * NIT_ + itile) * S_ + j];
        M = fmaxf(M, mv[itile]);
    }
    float L = 0.f;
    #pragma unroll
    for (int itile = 0; itile < NIT_; ++itile)
        L += s_p[((size_t)b * NIT_ + itile) * S_ + j] * __expf(mv[itile] - M);
    float invL = (L > 0.f) ? (1.f / L) : 0.f;
    #pragma unroll
    for (int itile = 0; itile < NIT_; ++itile)
        scl[((size_t)b * NIT_ + itile) * S_ + j] = __expf(mv[itile] - M) * invL;
}

// ---------------------------------------------------------------------------
// K3: out = rawE @ (scl .* vT) AND fused attn finalize (attn = rawE * scl)
// written from the same LDS-staged tiles. One pass over the attn matrix.
// ---------------------------------------------------------------------------
__global__ __launch_bounds__(256, 2) void av_gemm_kernel(
        const u16* __restrict__ vT, const float* __restrict__ scl,
        const u16* __restrict__ stageB, u16* __restrict__ attnB,
        float* __restrict__ attnF,
        u16* __restrict__ outB, float* __restrict__ outF,
        const int* __restrict__ flagp)
{
    __shared__ __align__(16) u16 lds_attn[128 * 128];   // rows of 16 chunks, pos = c ^ (row&15)
    __shared__ __align__(16) u16 lds_vt[64 * 128];      // rows of 16 chunks, pos = c ^ (d&15)
    const int fp32 = *flagp;
    const u16* srcE = fp32 ? stageB : attnB;
    const int t = threadIdx.x;
    const int lane = t & 63, w = t >> 6;
    const int it = blockIdx.x, b = blockIdx.y;
    const int i0 = it * 128;
    const int l15 = lane & 15;

    const int acp = t & 15;                       // position
    const int arow0 = t >> 4;                     // base row (rep adds 16)
    const int ac = acp ^ (arow0 & 15);            // logical chunk (const across reps)
    const int vpos = (t & 15) ^ (t >> 4);
    const int j8 = (t & 15) * 8;
    const size_t sclbase = ((size_t)b * NIT_ + it) * S_;

    f32x4 acc[2][4];
    #pragma unroll
    for (int a = 0; a < 2; ++a)
        #pragma unroll
        for (int c = 0; c < 4; ++c) acc[a][c] = (f32x4){0.f, 0.f, 0.f, 0.f};

    for (int jt = 0; jt < 16; ++jt) {
        const int j0 = jt * 128;
        __syncthreads();                          // protect prev iter's LDS reads
        const size_t abase = ((size_t)b * S_ + i0) * S_ + j0;
        #pragma unroll
        for (int rep = 0; rep < 8; ++rep) {
            int s = t + rep * 256;
            int row = arow0 + rep * 16;
            gl2lds16(srcE + abase + (size_t)row * S_ + ac * 8, lds_attn + s * 8);
        }
        // scl for vT staging chunk (j8) and for epilogue chunk (ac*8)
        float sc[8], esc[8];
        {
            const float4* sp = (const float4*)(scl + sclbase + j0 + j8);
            float4 s0 = sp[0], s1 = sp[1];
            sc[0] = s0.x; sc[1] = s0.y; sc[2] = s0.z; sc[3] = s0.w;
            sc[4] = s1.x; sc[5] = s1.y; sc[6] = s1.z; sc[7] = s1.w;
            const float4* ep = (const float4*)(scl + sclbase + j0 + ac * 8);
            float4 e0 = ep[0], e1 = ep[1];
            esc[0] = e0.x; esc[1] = e0.y; esc[2] = e0.z; esc[3] = e0.w;
            esc[4] = e1.x; esc[5] = e1.y; esc[6] = e1.z; esc[7] = e1.w;
        }
        #pragma unroll
        for (int rep = 0; rep < 4; ++rep) {
            int d = (t >> 4) + rep * 16;
            uint4 raw = *(const uint4*)(vT + ((size_t)b * 64 + d) * S_ + j0 + j8);
            unsigned wd[4] = {raw.x, raw.y, raw.z, raw.w};
            #pragma unroll
            for (int e2 = 0; e2 < 4; ++e2) {
                float f0 = bf2f((u16)(wd[e2] & 0xffffu)) * sc[e2 * 2];
                float f1 = bf2f((u16)(wd[e2] >> 16))     * sc[e2 * 2 + 1];
                wd[e2] = (unsigned)f2bf(f0) | ((unsigned)f2bf(f1) << 16);
            }
            uint4 pk; pk.x = wd[0]; pk.y = wd[1]; pk.z = wd[2]; pk.w = wd[3];
            *(uint4*)(lds_vt + d * 128 + vpos * 8) = pk;
        }
        __syncthreads();                          // drains gl2lds + ds_writes

        // ---- fused attn finalize: read back own raw-e chunks, scale, write ----
        #pragma unroll
        for (int rep = 0; rep < 8; ++rep) {
            int s = t + rep * 256;
            int row = arow0 + rep * 16;
            uint4 pk = *(const uint4*)(lds_attn + s * 8);
            unsigned wd[4] = {pk.x, pk.y, pk.z, pk.w};
            float f[8];
            f[0] = bf2f((u16)(wd[0] & 0xffffu)) * esc[0];
            f[1] = bf2f((u16)(wd[0] >> 16))     * esc[1];
            f[2] = bf2f((u16)(wd[1] & 0xffffu)) * esc[2];
            f[3] = bf2f((u16)(wd[1] >> 16))     * esc[3];
            f[4] = bf2f((u16)(wd[2] & 0xffffu)) * esc[4];
            f[5] = bf2f((u16)(wd[2] >> 16))     * esc[5];
            f[6] = bf2f((u16)(wd[3] & 0xffffu)) * esc[6];
            f[7] = bf2f((u16)(wd[3] >> 16))     * esc[7];
            size_t ga = abase + (size_t)row * S_ + ac * 8;
            if (fp32) {
                float4 o0, o1;
                o0.x = f[0]; o0.y = f[1]; o0.z = f[2]; o0.w = f[3];
                o1.x = f[4]; o1.y = f[5]; o1.z = f[6]; o1.w = f[7];
                *(float4*)(attnF + ga) = o0;
                *(float4*)(attnF + ga + 4) = o1;
            } else {
                uint4 o;
                o.x = (unsigned)f2bf(f[0]) | ((unsigned)f2bf(f[1]) << 16);
                o.y = (unsigned)f2bf(f[2]) | ((unsigned)f2bf(f[3]) << 16);
                o.z = (unsigned)f2bf(f[4]) | ((unsigned)f2bf(f[5]) << 16);
                o.w = (unsigned)f2bf(f[6]) | ((unsigned)f2bf(f[7]) << 16);
                *(uint4*)(attnB + ga) = o;
            }
        }

        #pragma unroll
        for (int ksj = 0; ksj < 4; ++ksj) {
            int ck = ksj * 4 + (lane >> 4);
            int pA = ck ^ l15;
            int rA0 = w * 32 + l15, rA1 = w * 32 + 16 + l15;
            bf16x8 a0 = *(const bf16x8*)(lds_attn + rA0 * 128 + pA * 8);
            bf16x8 a1 = *(const bf16x8*)(lds_attn + rA1 * 128 + pA * 8);
            bf16x8 bb[4];
            #pragma unroll
            for (int fc = 0; fc < 4; ++fc) {
                int d = fc * 16 + l15;
                bb[fc] = *(const bf16x8*)(lds_vt + d * 128 + pA * 8);
            }
            #pragma unroll
            for (int fc = 0; fc < 4; ++fc) {
                acc[0][fc] = __builtin_amdgcn_mfma_f32_16x16x32_bf16(a0, bb[fc], acc[0][fc], 0, 0, 0);
                acc[1][fc] = __builtin_amdgcn_mfma_f32_16x16x32_bf16(a1, bb[fc], acc[1][fc], 0, 0, 0);
            }
        }
    }
    #pragma unroll
    for (int fr = 0; fr < 2; ++fr)
        #pragma unroll
        for (int fc = 0; fc < 4; ++fc)
            #pragma unroll
            for (int reg = 0; reg < 4; ++reg) {
                int i = i0 + w * 32 + fr * 16 + (lane >> 4) * 4 + reg;
                int d = fc * 16 + l15;
                float v = acc[fr][fc][reg];
                size_t oo = ((size_t)b * S_ + i) * Z_ + d;
                if (fp32) outF[oo] = v;
                else      outB[oo] = f2bf(v);
            }
}

// ---------------------------------------------------------------------------
// K3-fallback (only when !use_stage): fused scale+AV.
// ---------------------------------------------------------------------------
__global__ __launch_bounds__(256, 2) void av_fallback_kernel(
        const u16* __restrict__ vT, const float* __restrict__ scl,
        u16* __restrict__ attnB, float* __restrict__ attnF,
        u16* __restrict__ outB, float* __restrict__ outF,
        const int* __restrict__ flagp)
{
    __shared__ __align__(16) u16 lds_attn[128 * 128];
    __shared__ __align__(16) u16 lds_vt[64 * 128];
    __shared__ float lds_scale[128];
    const int fp32 = *flagp;
    const int t = threadIdx.x;
    const int lane = t & 63, w = t >> 6;
    const int it = blockIdx.x, b = blockIdx.y;
    const int i0 = it * 128;
    const int l15 = lane & 15, koff = (lane >> 4) * 8;
    const size_t sclbase = ((size_t)b * NIT_ + it) * S_;

    f32x4 acc[2][4];
    #pragma unroll
    for (int a = 0; a < 2; ++a)
        #pragma unroll
        for (int c = 0; c < 4; ++c) acc[a][c] = (f32x4){0.f, 0.f, 0.f, 0.f};

    for (int jt = 0; jt < 16; ++jt) {
        const int j0 = jt * 128;
        __syncthreads();
        if (t < 128) lds_scale[t] = scl[sclbase + j0 + t];
        #pragma unroll
        for (int rep = 0; rep < 4; ++rep) {
            int s = t + rep * 256;
            int d = s >> 4, off = (s & 15) * 8;
            gl2lds16(vT + ((size_t)b * 64 + d) * S_ + j0 + off, lds_vt + s * 8);
        }
        __syncthreads();

        const size_t abase = ((size_t)b * S_ + i0) * S_ + j0;
        if (fp32) {
            #pragma unroll
            for (int rep = 0; rep < 8; ++rep) {
                int s = t + rep * 256;
                int row = s >> 4, off = (s & 15) * 8;
                float* gp = attnF + abase + (size_t)row * S_ + off;
                float4 p0 = *(const float4*)gp;
                float4 p1 = *(const float4*)(gp + 4);
                p0.x *= lds_scale[off + 0]; p0.y *= lds_scale[off + 1];
                p0.z *= lds_scale[off + 2]; p0.w *= lds_scale[off + 3];
                p1.x *= lds_scale[off + 4]; p1.y *= lds_scale[off + 5];
                p1.z *= lds_scale[off + 6]; p1.w *= lds_scale[off + 7];
                *(float4*)gp = p0;
                *(float4*)(gp + 4) = p1;
                uint4 pk;
                pk.x = (unsigned)f2bf(p0.x) | ((unsigned)f2bf(p0.y) << 16);
                pk.y = (unsigned)f2bf(p0.z) | ((unsigned)f2bf(p0.w) << 16);
                pk.z = (unsigned)f2bf(p1.x) | ((unsigned)f2bf(p1.y) << 16);
                pk.w = (unsigned)f2bf(p1.z) | ((unsigned)f2bf(p1.w) << 16);
                *(uint4*)(lds_attn + s * 8) = pk;
            }
        } else {
            #pragma unroll
            for (int rep = 0; rep < 8; ++rep) {
                int s = t + rep * 256;
                int row = s >> 4, off = (s & 15) * 8;
                size_t ga = abase + (size_t)row * S_ + off;
                uint4 pk = *(const uint4*)(attnB + ga);
                unsigned int wd[4] = {pk.x, pk.y, pk.z, pk.w};
                #pragma unroll
                for (int e2 = 0; e2 < 4; ++e2) {
                    float f0 = bf2f((u16)(wd[e2] & 0xffffu)) * lds_scale[off + e2 * 2];
                    float f1 = bf2f((u16)(wd[e2] >> 16))     * lds_scale[off + e2 * 2 + 1];
                    wd[e2] = (unsigned int)f2bf(f0) | ((unsigned int)f2bf(f1) << 16);
                }
                uint4 opk; opk.x = wd[0]; opk.y = wd[1]; opk.z = wd[2]; opk.w = wd[3];
                *(uint4*)(attnB + ga) = opk;
                *(uint4*)(lds_attn + s * 8) = opk;
            }
        }
        __syncthreads();

        #pragma unroll
        for (int ksj = 0; ksj < 4; ++ksj) {
            bf16x8 a0 = *(const bf16x8*)(lds_attn + (w * 32 +  0 + l15) * 128 + ksj * 32 + koff);
            bf16x8 a1 = *(const bf16x8*)(lds_attn + (w * 32 + 16 + l15) * 128 + ksj * 32 + koff);
            bf16x8 bb[4];
            #pragma unroll
            for (int fc = 0; fc < 4; ++fc)
                bb[fc] = *(const bf16x8*)(lds_vt + (fc * 16 + l15) * 128 + ksj * 32 + koff);
            #pragma unroll
            for (int fc = 0; fc < 4; ++fc) {
                acc[0][fc] = __builtin_amdgcn_mfma_f32_16x16x32_bf16(a0, bb[fc], acc[0][fc], 0, 0, 0);
                acc[1][fc] = __builtin_amdgcn_mfma_f32_16x16x32_bf16(a1, bb[fc], acc[1][fc], 0, 0, 0);
            }
        }
    }
    #pragma unroll
    for (int fr = 0; fr < 2; ++fr)
        #pragma unroll
        for (int fc = 0; fc < 4; ++fc)
            #pragma unroll
            for (int reg = 0; reg < 4; ++reg) {
                int i = i0 + w * 32 + fr * 16 + (lane >> 4) * 4 + reg;
                int d = fc * 16 + l15;
                float v = acc[fr][fc][reg];
                size_t oo = ((size_t)b * S_ + i) * Z_ + d;
                if (fp32) outF[oo] = v;
                else      outB[oo] = f2bf(v);
            }
}

// ---------------------------------------------------------------------------
extern "C" void kernel_launch(void* const* d_in, const int* in_sizes, int n_in,
                              void* d_out, int out_size, void* d_ws, size_t ws_size,
                              hipStream_t stream) {
    const void* enc    = d_in[0];
    const void* dec    = d_in[1];
    const void* latent = d_in[3];
    const void* mraw   = d_in[4];
    const void* Wq     = d_in[5];
    const void* Wk     = d_in[6];
    const void* Wv     = d_in[7];

    u16*   outB  = (u16*)d_out;
    float* outF  = (float*)d_out;
    u16*   attnB = outB + (size_t)B_ * S_ * Z_;
    float* attnF = outF + (size_t)B_ * S_ * Z_;
    float* m_p = (float*)d_out;                    // dead-until-av output0 head
    float* s_p = m_p + (size_t)B_ * NIT_ * S_;     // total 8 MB <= output0 region

    char* ws = (char*)d_ws;
    int*   flag  = (int*)ws;                                       // 256 B slot
    int*   maskI = (int*)(ws + 256);                               // 256 KB
    u16*   vT    = (u16*)((char*)maskI + (size_t)B_ * S_ * 4);     // 8 MB
    u16*   WqTh  = vT + (size_t)B_ * Z_ * S_;                      // 6 x 128 KB
    u16*   WqTl  = WqTh + H_ * H_;
    u16*   WkTh  = WqTl + H_ * H_;
    u16*   WkTl  = WkTh + H_ * H_;
    u16*   Gh    = WkTl + H_ * H_;
    u16*   Gl    = Gh + H_ * H_;
    float* scl   = (float*)(Gl + H_ * H_);                         // 4 MB
    char*  dyn   = (char*)(scl + (size_t)B_ * NIT_ * S_);

    const size_t fixed_bytes  = (size_t)(dyn - ws);                // ~13 MB
    const size_t per_batch    = (size_t)4 * S_ * H_ * 2;           // 4 MB
    const size_t xsplit_bytes = (size_t)4 * B_ * S_ * H_ * 2;      // 128 MB
    const size_t stage_bytes  = (size_t)B_ * S_ * S_ * 2;          // 256 MB

    long long avail = (long long)ws_size - (long long)fixed_bytes;
    int use_xsplit = 0, use_stage = 0;
    u16 *Xdh = 0, *Xdl = 0, *Xeh = 0, *Xel = 0, *stageB = 0;
    if (avail >= (long long)(xsplit_bytes + per_batch)) {
        use_xsplit = 1;
        Xdh = (u16*)dyn;
        Xdl = Xdh + (size_t)B_ * S_ * H_;
        Xeh = Xdl + (size_t)B_ * S_ * H_;
        Xel = Xeh + (size_t)B_ * S_ * H_;
        dyn += xsplit_bytes;
        avail -= (long long)xsplit_bytes;
    }
    if (avail >= (long long)(stage_bytes + per_batch)) {
        use_stage = 1;
        stageB = (u16*)dyn;
        dyn += stage_bytes;
        avail -= (long long)stage_bytes;
    }
    int g_b = (avail > 0) ? (int)(avail / (long long)per_batch) : 1;
    if (g_b < 1)  g_b = 1;
    if (g_b > 32) g_b = 32;

    u16* qh = (u16*)dyn;
    u16* ql = qh + (size_t)g_b * S_ * H_;
    u16* kh = ql + (size_t)g_b * S_ * H_;
    u16* kl = kh + (size_t)g_b * S_ * H_;

    detect_kernel<<<dim3(1), 256, 0, stream>>>((const u16*)Wq, flag);

    const int n_xs = use_xsplit ? 8192 : 0;
    prep_kernel<<<dim3(n_xs + 1024 + 128 + 256 + 256), 256, 0, stream>>>(
        flag, n_xs, dec, enc, Xdh, Xdl, Xeh, Xel,
        latent, Wv, vT, Wq, Wk, WqTh, WqTl, WkTh, WkTl, Gh, Gl, mraw, maskI);

    for (int b0 = 0; b0 < B_; b0 += g_b) {
        int g = (B_ - b0 < g_b) ? (B_ - b0) : g_b;
        size_t eoff = (size_t)b0 * S_ * H_;   // element offset, dtype-agnostic
        if (use_xsplit) {
            // G-path: q = dec (pre-split); only k' = enc @ G^T projected.
            proj_kernel<<<dim3(g * 16, 2, 1), 256, 0, stream>>>(
                flag, use_xsplit,
                (const float*)enc + eoff, (const u16*)enc + eoff,
                Xeh + eoff, Xel + eoff,
                Gh, Gl, kh, kl,
                (const float*)enc + eoff, (const u16*)enc + eoff,
                Xeh + eoff, Xel + eoff,
                Gh, Gl, kh, kl);
            qk_kernel<<<dim3(16, 16, g), 256, 0, stream>>>(
                Xdh + eoff, Xdl + eoff, kh, kl, maskI,
                attnB, attnF, stageB, use_stage, m_p, s_p, b0, flag);
        } else {
            proj_kernel<<<dim3(g * 16, 2, 2), 256, 0, stream>>>(
                flag, use_xsplit,
                (const float*)dec + eoff, (const u16*)dec + eoff,
                (u16*)0, (u16*)0, WqTh, WqTl, qh, ql,
                (const float*)enc + eoff, (const u16*)enc + eoff,
                (u16*)0, (u16*)0, WkTh, WkTl, kh, kl);
            qk_kernel<<<dim3(16, 16, g), 256, 0, stream>>>(
                qh, ql, kh, kl, maskI,
                attnB, attnF, stageB, use_stage, m_p, s_p, b0, flag);
        }
    }
    stats_kernel<<<dim3(256), 256, 0, stream>>>(m_p, s_p, scl);
    if (use_stage) {
        av_gemm_kernel<<<dim3(16, 32), 256, 0, stream>>>(vT, scl, stageB, attnB, attnF,
                                                         outB, outF, flag);
    } else {
        av_fallback_kernel<<<dim3(16, 32), 256, 0, stream>>>(vT, scl, attnB, attnF,
                                                             outB, outF, flag);
    }
}